// Round 18
// baseline (32.691 us; speedup 1.0000x reference)
//
#include <hip/hip_runtime.h>

// Problem constants (B=16, C=64, H=64, W=64, K=1024, D=64)
#define HWSZ   4096
#define CCH    64
#define KCB    1024
#define NROW   65536
#define NDTOT  4194304
#define MBLK   256             // main-path blocks (2 per CU)
#define BROWS  256             // rows per block (4 waves x 64 rows)

typedef __attribute__((ext_vector_type(8))) short short8;
typedef __attribute__((ext_vector_type(4))) float f32x4;

typedef const __attribute__((address_space(1))) unsigned gas_u32;
typedef __attribute__((address_space(3))) unsigned las_u32;

__device__ __forceinline__ unsigned short f2bf_rn(float x) {
    union { float f; unsigned u; } v; v.f = x;
    unsigned r = (v.u + 0x7fffu + ((v.u >> 16) & 1u)) >> 16;
    return (unsigned short)r;
}

// ---------- prep: E -> bf16 rows (PRE-SWIZZLED: dword ^ ((k&7)<<2)) + he2b ----------
__global__ __launch_bounds__(256) void vq_prep(const float* __restrict__ E,
                                               unsigned* __restrict__ Ebf,
                                               float* __restrict__ he2b) {
    int k = blockIdx.x * 256 + threadIdx.x;   // 0..1023
    const float4* ep = (const float4*)(E + (size_t)k * 64);
    float s = 0.f;
    const unsigned sw = ((unsigned)k & 7u) << 2;   // T2 swizzle on dword index
    #pragma unroll
    for (int c4 = 0; c4 < 16; ++c4) {
        float4 a = ep[c4];
        s += a.x * a.x + a.y * a.y + a.z * a.z + a.w * a.w;
        unsigned lo = (unsigned)f2bf_rn(a.x) | ((unsigned)f2bf_rn(a.y) << 16);
        unsigned hi = (unsigned)f2bf_rn(a.z) | ((unsigned)f2bf_rn(a.w) << 16);
        unsigned base = (unsigned)k * 32 + 2 * c4;
        Ebf[base ^ sw]       = lo;     // (base+1)^sw == (base^sw)+1 (sw bits >= 2)
        Ebf[(base + 1) ^ sw] = hi;
    }
    he2b[k] = 1.0f + 0.5f * s;
}

// ---------- main: 256 blocks x 256 thr; 2 blocks/CU; wave = 64 rows x all codes ----------
// Half-codebook 2-pass: LDS 64KB (codes [p*512, +512)) staged via global_load_lds,
// scan pass, restage other half (L2-hot), scan again. rt=4 (r17-proven, no spill)
// halves per-CU LDS-read volume vs r15; 2 blocks/CU overlap stage/A-build/scan/
// epilogue phases (r16 diagnostic: T_other ~23us was phase serialization at 1 blk/CU).
__global__ __launch_bounds__(256, 2) void vq_mfma(const float* __restrict__ z,
                                                  const float* __restrict__ E,
                                                  const short* __restrict__ Ebf,
                                                  const float* __restrict__ he2g,
                                                  float* __restrict__ out,
                                                  float* __restrict__ partial) {
    __shared__ short lbs[32768];       // 64 KB: half codebook (swizzled image)
    __shared__ float he2l[1024];       // 4 KB biases (all codes)
    __shared__ float wsum[4];

    const int t   = threadIdx.x;       // 0..255
    const int blk = blockIdx.x;        // 0..255
    const int n0  = blk * BROWS;
    const int bb  = n0 >> 12;
    const int wid = t >> 6, lane = t & 63, col = lane & 15, g = lane >> 4;
    const int hwb = (n0 & 4095) + wid * 64;          // wave's 64-row hw base
    const float* zw = z + (size_t)bb * CCH * HWSZ + hwb;

    // ---- stage half 0: 4096 x 16B slots, 16/thread (DMA, zero VGPRs) ----
    #pragma unroll
    for (int q = 0; q < 16; ++q) {
        int slot = q * 256 + t;        // per-wave dest = uniform base + lane*16  ✓
        __builtin_amdgcn_global_load_lds((gas_u32*)((const char*)Ebf + (size_t)slot * 16),
                                         (las_u32*)((char*)lbs + slot * 16), 16, 0, 0);
    }
    // ---- stage ALL he2: 256 x 16B slots, 1/thread ----
    __builtin_amdgcn_global_load_lds((gas_u32*)((const char*)he2g + (size_t)t * 16),
                                     (las_u32*)((char*)he2l + t * 16), 16, 0, 0);

    // ---- A-frags rt=4 (64 rows/wave) + z^2, from global (overlaps DMA);
    // per-rt fences cap the hoisted-load peak (r10/r12 spill lesson) ----
    float z2 = 0.f;
    short8 af[4][2];
    #pragma unroll
    for (int rt = 0; rt < 4; ++rt) {
        #pragma unroll
        for (int ch = 0; ch < 2; ++ch) {
            short8 a;
            #pragma unroll
            for (int j = 0; j < 8; ++j) {
                int c = ch * 32 + g * 8 + j;
                float v = zw[(size_t)c * HWSZ + rt * 16 + col];
                z2 = fmaf(v, v, z2);
                union { float f; unsigned u; } uu; uu.f = v;
                a[j] = (short)((uu.u >> 16) ^ 0x8000u);   // -z, bf16 truncation
            }
            af[rt][ch] = a;
        }
        asm volatile("" ::: "memory");
    }

    __syncthreads();   // drains DMAs (half 0 + he2), publishes LDS

    float pk[4][4];
    #pragma unroll
    for (int rt = 0; rt < 4; ++rt)
        #pragma unroll
        for (int r = 0; r < 4; ++r) pk[rt][r] = 3.0e38f;

    // per-lane swizzled LDS read offsets (shorts); code&7 == col&7 within a tile
    const int swz = (col & 7) << 3;
    const int ro0 = col * 64 + ((g * 8) ^ swz);
    const int ro1 = col * 64 + ((32 + g * 8) ^ swz);

    // ---- 2 passes over codebook halves ----
    #pragma unroll 1
    for (int p = 0; p < 2; ++p) {
        if (p == 1) {
            __syncthreads();           // all waves done reading half 0
            #pragma unroll
            for (int q = 0; q < 16; ++q) {
                int slot = q * 256 + t;
                __builtin_amdgcn_global_load_lds(
                    (gas_u32*)((const char*)Ebf + 65536 + (size_t)slot * 16),
                    (las_u32*)((char*)lbs + slot * 16), 16, 0, 0);
            }
            __syncthreads();           // compiler emits vmcnt(0) drain before barrier
        }

        const int cbase = p * 512;     // global code base of this half

        // ---- scan: 16 code-tile pairs; 4 ds_read_b128 -> 16 MFMA each ----
        #pragma unroll 2
        for (int cp = 0; cp < 16; ++cp) {
            const int ct0 = cp * 2, ct1 = ct0 + 1;         // local tiles 0..31
            const short* Lb0 = lbs + ct0 * 1024;
            const short* Lb1 = lbs + ct1 * 1024;
            short8 b00 = *(const short8*)(Lb0 + ro0);
            short8 b01 = *(const short8*)(Lb0 + ro1);
            short8 b10 = *(const short8*)(Lb1 + ro0);
            short8 b11 = *(const short8*)(Lb1 + ro1);
            const unsigned code0 = (unsigned)(cbase + ct0 * 16 + col);
            const unsigned code1 = code0 + 16;
            const float h0 = he2l[code0];                   // broadcast reads
            const float h1 = he2l[code1];
            f32x4 hv0 = {h0, h0, h0, h0};
            f32x4 hv1 = {h1, h1, h1, h1};
            #pragma unroll
            for (int rt = 0; rt < 4; ++rt) {
                f32x4 a0 = __builtin_amdgcn_mfma_f32_16x16x32_bf16(af[rt][0], b00, hv0, 0, 0, 0);
                a0 = __builtin_amdgcn_mfma_f32_16x16x32_bf16(af[rt][1], b01, a0, 0, 0, 0);
                f32x4 a1 = __builtin_amdgcn_mfma_f32_16x16x32_bf16(af[rt][0], b10, hv1, 0, 0, 0);
                a1 = __builtin_amdgcn_mfma_f32_16x16x32_bf16(af[rt][1], b11, a1, 0, 0, 0);
                #pragma unroll
                for (int r = 0; r < 4; ++r) {
                    union { float f; unsigned u; } m0, m1;
                    m0.f = a0[r]; m0.u = (m0.u & 0xFFFFFC00u) | code0;   // v_and_or_b32
                    m1.f = a1[r]; m1.u = (m1.u & 0xFFFFFC00u) | code1;
                    pk[rt][r] = fminf(fminf(pk[rt][r], m0.f), m1.f);     // v_min3_f32
                }
            }
        }
    }

    // ---- butterfly min over 16 code-columns ----
    #pragma unroll
    for (int rt = 0; rt < 4; ++rt) {
        #pragma unroll
        for (int r = 0; r < 4; ++r) {
            float d = pk[rt][r];
            #pragma unroll
            for (int mask = 1; mask < 16; mask <<= 1)
                d = fminf(d, __shfl_xor(d, mask, 64));
            pk[rt][r] = d;
        }
    }

    // ---- epilogue: output = E rows, loss from winning scores ----
    float lsum = z2;
    const int rowbase = n0 + wid * 64;
    #pragma unroll
    for (int rt = 0; rt < 4; ++rt) {
        #pragma unroll
        for (int r = 0; r < 4; ++r) {
            union { float f; unsigned u; } b; b.f = pk[rt][r];
            unsigned kk = b.u & 1023u;
            if (col == 0) {                              // count each row's score once
                union { unsigned u; float f; } sc; sc.u = b.u & 0xFFFFFC00u;
                lsum += 2.0f * (sc.f - 1.0f);            // ||e||^2 - 2 z.e
            }
            int row = rt * 16 + g * 4 + r;
            float4 qv = *(const float4*)(E + (size_t)kk * 64 + col * 4);
            *(float4*)(out + ((size_t)(rowbase + row)) * 64 + col * 4) = qv;
        }
    }

    #pragma unroll
    for (int off = 32; off >= 1; off >>= 1) lsum += __shfl_down(lsum, off, 64);
    if (lane == 0) wsum[wid] = lsum;
    __syncthreads();
    if (t == 0) partial[blk] = (wsum[0] + wsum[1]) + (wsum[2] + wsum[3]);
}

// ---------- fallback fp32 path (round-1, correctness-proven) ----------
__global__ __launch_bounds__(64) void vq_init(float* out) {
    if (threadIdx.x == 0) { out[NDTOT] = 0.0f; out[NDTOT + 1] = 0.0f; }
}

__global__ __launch_bounds__(256, 4) void vq_main_fp32(const float* __restrict__ z,
                                                       const float* __restrict__ E,
                                                       float* __restrict__ out,
                                                       float* __restrict__ partial) {
    __shared__ float zs[64][65];
    __shared__ float e2s[KCB];
    __shared__ float wmin[4][64];
    __shared__ int   widx[4][64];
    __shared__ int   rowidx[64];
    __shared__ float wsum[4];

    const int t   = threadIdx.x;
    const int blk = blockIdx.x;
    const int n0  = blk << 6;
    const int bb  = n0 >> 12;
    const int hw0 = n0 & 4095;
    const float* zb = z + (size_t)bb * CCH * HWSZ + hw0;

    #pragma unroll
    for (int j = 0; j < 16; ++j) {
        int f = t + 256 * j;
        int c = f >> 6, i = f & 63;
        zs[c][i] = zb[(size_t)c * HWSZ + i];
    }
    for (int qq = t; qq < KCB; qq += 256) {
        const float4* ep = (const float4*)(E + (size_t)qq * 64);
        float s0 = 0.f;
        #pragma unroll
        for (int c4 = 0; c4 < 16; ++c4) {
            float4 a = ep[c4];
            s0 += a.x * a.x + a.y * a.y + a.z * a.z + a.w * a.w;
        }
        e2s[qq] = s0;
    }
    __syncthreads();

    const int i   = t & 63;
    const int wid = t >> 6;
    float zr[64];
    #pragma unroll
    for (int c = 0; c < 64; ++c) zr[c] = zs[c][i];

    float best = 3.4e38f;
    int   bi = 0;
    const int k0 = wid << 8;
    const float* Ew = E + (size_t)k0 * 64;
    for (int kk = 0; kk < 256; ++kk) {
        const float4* ek = (const float4*)(Ew + (size_t)kk * 64);
        float d0 = 0.f, d1 = 0.f, d2 = 0.f, d3 = 0.f;
        #pragma unroll
        for (int c4 = 0; c4 < 16; ++c4) {
            float4 a = ek[c4];
            d0 = fmaf(a.x, zr[4 * c4 + 0], d0);
            d1 = fmaf(a.y, zr[4 * c4 + 1], d1);
            d2 = fmaf(a.z, zr[4 * c4 + 2], d2);
            d3 = fmaf(a.w, zr[4 * c4 + 3], d3);
        }
        float dot  = (d0 + d1) + (d2 + d3);
        float dist = fmaf(-2.0f, dot, e2s[k0 + kk]);
        if (dist < best) { best = dist; bi = k0 + kk; }
    }
    wmin[wid][i] = best; widx[wid][i] = bi;
    __syncthreads();
    if (t < 64) {
        float m = wmin[0][t]; int ix = widx[0][t];
        #pragma unroll
        for (int w = 1; w < 4; ++w) {
            float v = wmin[w][t]; int x = widx[w][t];
            if (v < m) { m = v; ix = x; }
        }
        rowidx[t] = ix;
    }
    __syncthreads();

    float lsum = 0.f;
    const size_t base = (size_t)blk * 4096;
    float* oflat = out + base;
    #pragma unroll
    for (int j = 0; j < 16; ++j) {
        int f  = t + 256 * j;
        int nl = f >> 6, d = f & 63;
        int k  = rowidx[nl];
        float qv = E[(size_t)k * 64 + d];
        float zf = zs[d][nl];
        float df = qv - zf;
        lsum += df * df;
        oflat[f] = qv;
    }
    #pragma unroll
    for (int off = 32; off >= 1; off >>= 1) lsum += __shfl_down(lsum, off, 64);
    if (i == 0) wsum[wid] = lsum;
    __syncthreads();
    if (t == 0) {
        float s = (wsum[0] + wsum[1]) + (wsum[2] + wsum[3]);
        if (partial) partial[blk] = s;
        else         atomicAdd(&out[NDTOT + 1], s);
    }
}

__global__ __launch_bounds__(256) void vq_fin(const float* __restrict__ partial,
                                              float* __restrict__ out, int npart) {
    if (npart > 0) {
        __shared__ float ps[256];
        float s = 0.f;
        for (int qq = threadIdx.x; qq < npart; qq += 256) s += partial[qq];
        ps[threadIdx.x] = s;
        __syncthreads();
        for (int st = 128; st >= 1; st >>= 1) {
            if (threadIdx.x < st) ps[threadIdx.x] += ps[threadIdx.x + st];
            __syncthreads();
        }
        if (threadIdx.x == 0) {
            float mse = ps[0] / (float)NDTOT;
            out[NDTOT]     = 0.25f * mse;   // commitment_loss
            out[NDTOT + 1] = mse;           // codebook_loss
        }
    } else {
        if (threadIdx.x == 0) {
            float mse = out[NDTOT + 1] / (float)NDTOT;
            out[NDTOT]     = 0.25f * mse;
            out[NDTOT + 1] = mse;
        }
    }
}

extern "C" void kernel_launch(void* const* d_in, const int* in_sizes, int n_in,
                              void* d_out, int out_size, void* d_ws, size_t ws_size,
                              hipStream_t stream) {
    const float* z = (const float*)d_in[0];
    const float* E = (const float*)d_in[1];
    float* out = (float*)d_out;

    const size_t EBF_BYTES = (size_t)KCB * 64 * 2;                 // 131072
    const size_t need = EBF_BYTES + 4096 + MBLK * sizeof(float);   // Ebf + he2b + partial

    if (ws_size >= need) {
        unsigned* EbfU = (unsigned*)d_ws;
        short* Ebf  = (short*)d_ws;
        float* he2b = (float*)((char*)d_ws + EBF_BYTES);
        float* partial = (float*)((char*)d_ws + EBF_BYTES + 4096);
        hipLaunchKernelGGL(vq_prep, dim3(4), dim3(256), 0, stream, E, EbfU, he2b);
        hipLaunchKernelGGL(vq_mfma, dim3(MBLK), dim3(256), 0, stream,
                           z, E, Ebf, he2b, out, partial);
        hipLaunchKernelGGL(vq_fin, dim3(1), dim3(256), 0, stream, partial, out, MBLK);
    } else {
        hipLaunchKernelGGL(vq_init, dim3(1), dim3(64), 0, stream, out);
        hipLaunchKernelGGL(vq_main_fp32, dim3(1024), dim3(256), 0, stream, z, E, out, nullptr);
        hipLaunchKernelGGL(vq_fin, dim3(1), dim3(256), 0, stream, nullptr, out, 0);
    }
}

// Round 19
// 30.486 us; speedup vs baseline: 1.0723x; 1.0723x over previous
//
#include <hip/hip_runtime.h>

// Problem constants (B=16, C=64, H=64, W=64, K=1024, D=64)
#define HWSZ   4096
#define CCH    64
#define KCB    1024
#define NROW   65536
#define NDTOT  4194304
#define MBLK   256             // main-path blocks (1 per CU)
#define BROWS  256             // rows per block (4 waves x 64 rows)

typedef __attribute__((ext_vector_type(8))) short short8;
typedef __attribute__((ext_vector_type(4))) float f32x4;

typedef const __attribute__((address_space(1))) unsigned gas_u32;
typedef __attribute__((address_space(3))) unsigned las_u32;

__device__ __forceinline__ unsigned short f2bf_rn(float x) {
    union { float f; unsigned u; } v; v.f = x;
    unsigned r = (v.u + 0x7fffu + ((v.u >> 16) & 1u)) >> 16;
    return (unsigned short)r;
}

// ---------- prep: 16 blocks, 4 threads/code: E -> swizzled bf16 + he2b ----------
__global__ __launch_bounds__(256) void vq_prep(const float* __restrict__ E,
                                               unsigned* __restrict__ Ebf,
                                               float* __restrict__ he2b) {
    const int t = threadIdx.x;
    const int gid  = blockIdx.x * 256 + t;
    const int code = gid >> 2;           // 0..1023
    const int part = gid & 3;
    const float4* ep = (const float4*)(E + (size_t)code * 64 + part * 16);
    const unsigned sw = ((unsigned)code & 7u) << 2;   // T2 swizzle on dword index
    float s = 0.f;
    #pragma unroll
    for (int q = 0; q < 4; ++q) {
        float4 a = ep[q];
        s += a.x * a.x + a.y * a.y + a.z * a.z + a.w * a.w;
        unsigned lo = (unsigned)f2bf_rn(a.x) | ((unsigned)f2bf_rn(a.y) << 16);
        unsigned hi = (unsigned)f2bf_rn(a.z) | ((unsigned)f2bf_rn(a.w) << 16);
        unsigned base = (unsigned)code * 32 + part * 8 + q * 2;
        Ebf[base ^ sw]       = lo;       // (base+1)^sw == (base^sw)+1 (sw bits >= 2)
        Ebf[(base + 1) ^ sw] = hi;
    }
    s += __shfl_xor(s, 1, 64);
    s += __shfl_xor(s, 2, 64);
    if (part == 0) he2b[code] = 1.0f + 0.5f * s;
}

// ---------- main: 256 blocks x 256 thr (1/CU); wave = 64 rows x all 1024 codes ----------
// r19 = r17 scan geometry (rt=4: per-CU LDS-read volume 512KB, half of r15/r18's
// 1MB -> scan ~3us) + r15 staging path (whole 128KB codebook + he2 via
// global_load_lds DMA, zero staging VGPRs -- not r17's per-block VALU conversion).
__global__ __launch_bounds__(256, 2) void vq_mfma(const float* __restrict__ z,
                                                  const float* __restrict__ E,
                                                  const short* __restrict__ Ebf,
                                                  const float* __restrict__ he2g,
                                                  float* __restrict__ out,
                                                  float* __restrict__ partial) {
    __shared__ short lbs[65536];       // 128 KB: full swizzled codebook image
    __shared__ float he2l[1024];       // 4 KB biases
    __shared__ float wsum[4];

    const int t   = threadIdx.x;       // 0..255
    const int blk = blockIdx.x;        // 0..255
    const int n0  = blk * BROWS;
    const int bb  = n0 >> 12;
    const int wid = t >> 6, lane = t & 63, col = lane & 15, g = lane >> 4;
    const int hwb = (n0 & 4095) + wid * 64;          // wave's 64-row hw base
    const float* zw = z + (size_t)bb * CCH * HWSZ + hwb;

    // ---- stage full codebook: 8192 x 16B slots, 32 per thread (DMA, zero VGPRs) ----
    #pragma unroll
    for (int q = 0; q < 32; ++q) {
        int slot = q * 256 + t;        // dest = wave-uniform base + lane*16  ✓
        __builtin_amdgcn_global_load_lds((gas_u32*)((const char*)Ebf + (size_t)slot * 16),
                                         (las_u32*)((char*)lbs + slot * 16), 16, 0, 0);
    }
    // ---- stage he2: 256 x 16B slots, 1 per thread ----
    __builtin_amdgcn_global_load_lds((gas_u32*)((const char*)he2g + (size_t)t * 16),
                                     (las_u32*)((char*)he2l + t * 16), 16, 0, 0);

    // ---- A-frags rt=4 (64 rows/wave) + z^2, from global (overlaps DMA);
    // per-rt fences cap the hoisted-load VGPR peak (r10/r12 spill lesson) ----
    float z2 = 0.f;
    short8 af[4][2];
    #pragma unroll
    for (int rt = 0; rt < 4; ++rt) {
        #pragma unroll
        for (int ch = 0; ch < 2; ++ch) {
            short8 a;
            #pragma unroll
            for (int j = 0; j < 8; ++j) {
                int c = ch * 32 + g * 8 + j;
                float v = zw[(size_t)c * HWSZ + rt * 16 + col];
                z2 = fmaf(v, v, z2);
                union { float f; unsigned u; } uu; uu.f = v;
                a[j] = (short)((uu.u >> 16) ^ 0x8000u);   // -z, bf16 truncation
            }
            af[rt][ch] = a;
        }
        asm volatile("" ::: "memory");
    }

    __syncthreads();   // compiler emits vmcnt(0) drain before s_barrier: DMAs landed

    float pk[4][4];
    #pragma unroll
    for (int rt = 0; rt < 4; ++rt)
        #pragma unroll
        for (int r = 0; r < 4; ++r) pk[rt][r] = 3.0e38f;

    // per-lane swizzled LDS read offsets (shorts); code&7 == col&7 within a tile
    const int swz = (col & 7) << 3;
    const int ro0 = col * 64 + ((g * 8) ^ swz);
    const int ro1 = col * 64 + ((32 + g * 8) ^ swz);

    // ---- barrier-free scan: 32 code-tile pairs; 4 ds_read_b128 -> 16 MFMA each ----
    #pragma unroll 2
    for (int cp = 0; cp < 32; ++cp) {
        const int ct0 = cp * 2, ct1 = ct0 + 1;
        const short* Lb0 = lbs + ct0 * 1024;
        const short* Lb1 = lbs + ct1 * 1024;
        short8 b00 = *(const short8*)(Lb0 + ro0);
        short8 b01 = *(const short8*)(Lb0 + ro1);
        short8 b10 = *(const short8*)(Lb1 + ro0);
        short8 b11 = *(const short8*)(Lb1 + ro1);
        const float h0 = he2l[ct0 * 16 + col];       // broadcast reads
        const float h1 = he2l[ct1 * 16 + col];
        const unsigned code0 = (unsigned)(ct0 * 16 + col);
        const unsigned code1 = code0 + 16;
        f32x4 hv0 = {h0, h0, h0, h0};
        f32x4 hv1 = {h1, h1, h1, h1};
        #pragma unroll
        for (int rt = 0; rt < 4; ++rt) {
            f32x4 a0 = __builtin_amdgcn_mfma_f32_16x16x32_bf16(af[rt][0], b00, hv0, 0, 0, 0);
            a0 = __builtin_amdgcn_mfma_f32_16x16x32_bf16(af[rt][1], b01, a0, 0, 0, 0);
            f32x4 a1 = __builtin_amdgcn_mfma_f32_16x16x32_bf16(af[rt][0], b10, hv1, 0, 0, 0);
            a1 = __builtin_amdgcn_mfma_f32_16x16x32_bf16(af[rt][1], b11, a1, 0, 0, 0);
            #pragma unroll
            for (int r = 0; r < 4; ++r) {
                union { float f; unsigned u; } m0, m1;
                m0.f = a0[r]; m0.u = (m0.u & 0xFFFFFC00u) | code0;   // v_and_or_b32
                m1.f = a1[r]; m1.u = (m1.u & 0xFFFFFC00u) | code1;
                pk[rt][r] = fminf(fminf(pk[rt][r], m0.f), m1.f);     // v_min3_f32
            }
        }
    }

    // ---- butterfly min over 16 code-columns ----
    #pragma unroll
    for (int rt = 0; rt < 4; ++rt) {
        #pragma unroll
        for (int r = 0; r < 4; ++r) {
            float d = pk[rt][r];
            #pragma unroll
            for (int mask = 1; mask < 16; mask <<= 1)
                d = fminf(d, __shfl_xor(d, mask, 64));
            pk[rt][r] = d;
        }
    }

    // ---- epilogue: output = E rows (== z + (q - z) to 1 ulp), loss from scores ----
    float lsum = z2;
    const int rowbase = n0 + wid * 64;
    #pragma unroll
    for (int rt = 0; rt < 4; ++rt) {
        #pragma unroll
        for (int r = 0; r < 4; ++r) {
            union { float f; unsigned u; } b; b.f = pk[rt][r];
            unsigned kk = b.u & 1023u;
            if (col == 0) {                              // count each row's score once
                union { unsigned u; float f; } sc; sc.u = b.u & 0xFFFFFC00u;
                lsum += 2.0f * (sc.f - 1.0f);            // ||e||^2 - 2 z.e
            }
            int row = rt * 16 + g * 4 + r;
            float4 qv = *(const float4*)(E + (size_t)kk * 64 + col * 4);
            *(float4*)(out + ((size_t)(rowbase + row)) * 64 + col * 4) = qv;
        }
    }

    #pragma unroll
    for (int off = 32; off >= 1; off >>= 1) lsum += __shfl_down(lsum, off, 64);
    if (lane == 0) wsum[wid] = lsum;
    __syncthreads();
    if (t == 0) partial[blk] = (wsum[0] + wsum[1]) + (wsum[2] + wsum[3]);
}

// ---------- fallback fp32 path (round-1, correctness-proven) ----------
__global__ __launch_bounds__(64) void vq_init(float* out) {
    if (threadIdx.x == 0) { out[NDTOT] = 0.0f; out[NDTOT + 1] = 0.0f; }
}

__global__ __launch_bounds__(256, 4) void vq_main_fp32(const float* __restrict__ z,
                                                       const float* __restrict__ E,
                                                       float* __restrict__ out,
                                                       float* __restrict__ partial) {
    __shared__ float zs[64][65];
    __shared__ float e2s[KCB];
    __shared__ float wmin[4][64];
    __shared__ int   widx[4][64];
    __shared__ int   rowidx[64];
    __shared__ float wsum[4];

    const int t   = threadIdx.x;
    const int blk = blockIdx.x;
    const int n0  = blk << 6;
    const int bb  = n0 >> 12;
    const int hw0 = n0 & 4095;
    const float* zb = z + (size_t)bb * CCH * HWSZ + hw0;

    #pragma unroll
    for (int j = 0; j < 16; ++j) {
        int f = t + 256 * j;
        int c = f >> 6, i = f & 63;
        zs[c][i] = zb[(size_t)c * HWSZ + i];
    }
    for (int qq = t; qq < KCB; qq += 256) {
        const float4* ep = (const float4*)(E + (size_t)qq * 64);
        float s0 = 0.f;
        #pragma unroll
        for (int c4 = 0; c4 < 16; ++c4) {
            float4 a = ep[c4];
            s0 += a.x * a.x + a.y * a.y + a.z * a.z + a.w * a.w;
        }
        e2s[qq] = s0;
    }
    __syncthreads();

    const int i   = t & 63;
    const int wid = t >> 6;
    float zr[64];
    #pragma unroll
    for (int c = 0; c < 64; ++c) zr[c] = zs[c][i];

    float best = 3.4e38f;
    int   bi = 0;
    const int k0 = wid << 8;
    const float* Ew = E + (size_t)k0 * 64;
    for (int kk = 0; kk < 256; ++kk) {
        const float4* ek = (const float4*)(Ew + (size_t)kk * 64);
        float d0 = 0.f, d1 = 0.f, d2 = 0.f, d3 = 0.f;
        #pragma unroll
        for (int c4 = 0; c4 < 16; ++c4) {
            float4 a = ek[c4];
            d0 = fmaf(a.x, zr[4 * c4 + 0], d0);
            d1 = fmaf(a.y, zr[4 * c4 + 1], d1);
            d2 = fmaf(a.z, zr[4 * c4 + 2], d2);
            d3 = fmaf(a.w, zr[4 * c4 + 3], d3);
        }
        float dot  = (d0 + d1) + (d2 + d3);
        float dist = fmaf(-2.0f, dot, e2s[k0 + kk]);
        if (dist < best) { best = dist; bi = k0 + kk; }
    }
    wmin[wid][i] = best; widx[wid][i] = bi;
    __syncthreads();
    if (t < 64) {
        float m = wmin[0][t]; int ix = widx[0][t];
        #pragma unroll
        for (int w = 1; w < 4; ++w) {
            float v = wmin[w][t]; int x = widx[w][t];
            if (v < m) { m = v; ix = x; }
        }
        rowidx[t] = ix;
    }
    __syncthreads();

    float lsum = 0.f;
    const size_t base = (size_t)blk * 4096;
    float* oflat = out + base;
    #pragma unroll
    for (int j = 0; j < 16; ++j) {
        int f  = t + 256 * j;
        int nl = f >> 6, d = f & 63;
        int k  = rowidx[nl];
        float qv = E[(size_t)k * 64 + d];
        float zf = zs[d][nl];
        float df = qv - zf;
        lsum += df * df;
        oflat[f] = qv;
    }
    #pragma unroll
    for (int off = 32; off >= 1; off >>= 1) lsum += __shfl_down(lsum, off, 64);
    if (i == 0) wsum[wid] = lsum;
    __syncthreads();
    if (t == 0) {
        float s = (wsum[0] + wsum[1]) + (wsum[2] + wsum[3]);
        if (partial) partial[blk] = s;
        else         atomicAdd(&out[NDTOT + 1], s);
    }
}

__global__ __launch_bounds__(256) void vq_fin(const float* __restrict__ partial,
                                              float* __restrict__ out, int npart) {
    if (npart > 0) {
        __shared__ float ps[256];
        float s = 0.f;
        for (int qq = threadIdx.x; qq < npart; qq += 256) s += partial[qq];
        ps[threadIdx.x] = s;
        __syncthreads();
        for (int st = 128; st >= 1; st >>= 1) {
            if (threadIdx.x < st) ps[threadIdx.x] += ps[threadIdx.x + st];
            __syncthreads();
        }
        if (threadIdx.x == 0) {
            float mse = ps[0] / (float)NDTOT;
            out[NDTOT]     = 0.25f * mse;   // commitment_loss
            out[NDTOT + 1] = mse;           // codebook_loss
        }
    } else {
        if (threadIdx.x == 0) {
            float mse = out[NDTOT + 1] / (float)NDTOT;
            out[NDTOT]     = 0.25f * mse;
            out[NDTOT + 1] = mse;
        }
    }
}

extern "C" void kernel_launch(void* const* d_in, const int* in_sizes, int n_in,
                              void* d_out, int out_size, void* d_ws, size_t ws_size,
                              hipStream_t stream) {
    const float* z = (const float*)d_in[0];
    const float* E = (const float*)d_in[1];
    float* out = (float*)d_out;

    const size_t EBF_BYTES = (size_t)KCB * 64 * 2;                 // 131072
    const size_t need = EBF_BYTES + 4096 + MBLK * sizeof(float);   // Ebf + he2b + partial

    if (ws_size >= need) {
        unsigned* EbfU = (unsigned*)d_ws;
        short* Ebf  = (short*)d_ws;
        float* he2b = (float*)((char*)d_ws + EBF_BYTES);
        float* partial = (float*)((char*)d_ws + EBF_BYTES + 4096);
        hipLaunchKernelGGL(vq_prep, dim3(16), dim3(256), 0, stream, E, EbfU, he2b);
        hipLaunchKernelGGL(vq_mfma, dim3(MBLK), dim3(256), 0, stream,
                           z, E, Ebf, he2b, out, partial);
        hipLaunchKernelGGL(vq_fin, dim3(1), dim3(256), 0, stream, partial, out, MBLK);
    } else {
        hipLaunchKernelGGL(vq_init, dim3(1), dim3(64), 0, stream, out);
        hipLaunchKernelGGL(vq_main_fp32, dim3(1024), dim3(256), 0, stream, z, E, out, nullptr);
        hipLaunchKernelGGL(vq_fin, dim3(1), dim3(256), 0, stream, nullptr, out, 0);
    }
}